// Round 1
// baseline (381.367 us; speedup 1.0000x reference)
//
#include <hip/hip_runtime.h>
#include <math.h>

#define B_    16
#define C_    256
#define H_    64
#define W_    64
#define N_    4096
#define HEADS_ 4
#define KK_   16
#define VV_   64
#define M_    7
#define PAD_  3
#define OTOT_ 144   // 64 q + 16 k + 64 v channels
#define NG_   36    // 36 groups of 4 channels
#define EPS_  1e-5f
#define VSPLIT_ 4

// ---------------------------------------------------------------------------
// K1: fused projection GEMM. proj[b, o, n] = sum_c W[o,c] * x[b,c,n]
// o in [0,144): 0-63 = q (wq), 64-79 = k (wk), 80-143 = v (wv)
// Each block: one (b, o-tile of 16, n-tile of 1024). Each thread: 4 positions.
// ---------------------------------------------------------------------------
__global__ __launch_bounds__(256) void k_proj(const float* __restrict__ x,
    const float* __restrict__ wq, const float* __restrict__ wk,
    const float* __restrict__ wv, float* __restrict__ proj) {
  __shared__ float sw[16][256];
  const int tid = threadIdx.x;
  const int o0  = blockIdx.y * 16;
  const int b   = blockIdx.z;
  const int n0  = blockIdx.x * 1024 + tid;

  for (int r = 0; r < 16; ++r) {
    int o = o0 + r;
    const float* wrow = (o < 64) ? (wq + o * C_)
                       : ((o < 80) ? (wk + (o - 64) * C_) : (wv + (o - 80) * C_));
    sw[r][tid] = wrow[tid];  // blockDim == C_ == 256
  }
  __syncthreads();

  float acc[16][4];
  #pragma unroll
  for (int r = 0; r < 16; ++r)
    #pragma unroll
    for (int p = 0; p < 4; ++p) acc[r][p] = 0.f;

  const float* xb = x + (size_t)b * C_ * N_;
  for (int c0 = 0; c0 < C_; c0 += 4) {
    float xv[4][4];
    #pragma unroll
    for (int i = 0; i < 4; ++i)
      #pragma unroll
      for (int p = 0; p < 4; ++p)
        xv[i][p] = xb[(size_t)(c0 + i) * N_ + n0 + p * 256];
    #pragma unroll
    for (int i = 0; i < 4; ++i) {
      #pragma unroll
      for (int r = 0; r < 16; ++r) {
        float w = sw[r][c0 + i];
        #pragma unroll
        for (int p = 0; p < 4; ++p) acc[r][p] += w * xv[i][p];
      }
    }
  }

  float* pb = proj + ((size_t)b * OTOT_ + o0) * N_ + n0;
  #pragma unroll
  for (int r = 0; r < 16; ++r)
    #pragma unroll
    for (int p = 0; p < 4; ++p)
      pb[(size_t)r * N_ + p * 256] = acc[r][p];
}

// ---------------------------------------------------------------------------
// K2: GroupNorm stats. One block per (b, group). Each group = 4 consecutive
// channels x 4096 positions (contiguous 16384 floats in proj).
// ---------------------------------------------------------------------------
__global__ __launch_bounds__(256) void k_stats(const float* __restrict__ proj,
    float* __restrict__ meanp, float* __restrict__ rstdp) {
  const int bg = blockIdx.x;           // b*36 + g
  const int b = bg / NG_, g = bg % NG_;
  const float* p = proj + ((size_t)b * OTOT_ + g * 4) * N_;
  float s = 0.f, s2 = 0.f;
  for (int i = threadIdx.x; i < 4 * N_; i += 256) {
    float v = p[i];
    s += v; s2 += v * v;
  }
  __shared__ float rs[256], rq[256];
  rs[threadIdx.x] = s; rq[threadIdx.x] = s2;
  __syncthreads();
  for (int off = 128; off > 0; off >>= 1) {
    if (threadIdx.x < off) {
      rs[threadIdx.x] += rs[threadIdx.x + off];
      rq[threadIdx.x] += rq[threadIdx.x + off];
    }
    __syncthreads();
  }
  if (threadIdx.x == 0) {
    float m   = rs[0] * (1.f / 16384.f);
    float var = rq[0] * (1.f / 16384.f) - m * m;
    meanp[bg] = m;
    rstdp[bg] = rsqrtf(var + EPS_);
  }
}

// ---------------------------------------------------------------------------
// K3: k GroupNorm-apply + softmax over n. One block per (b, kk) row.
// ---------------------------------------------------------------------------
__global__ __launch_bounds__(256) void k_softmax(const float* __restrict__ proj,
    const float* __restrict__ meanp, const float* __restrict__ rstdp,
    const float* __restrict__ gkg, const float* __restrict__ gkb,
    float* __restrict__ ksm) {
  const int bk = blockIdx.x;  // b*16 + kk
  const int b = bk >> 4, kk = bk & 15;
  const int g = 16 + (kk >> 2);
  const float mu = meanp[b * NG_ + g], rs = rstdp[b * NG_ + g];
  const float ga = gkg[kk], be = gkb[kk];
  const float* p = proj + ((size_t)b * OTOT_ + 64 + kk) * N_;
  float* o = ksm + ((size_t)b * KK_ + kk) * N_;

  float xn[16];
  float m = -1e30f;
  #pragma unroll
  for (int i = 0; i < 16; ++i) {
    float v = (p[threadIdx.x + i * 256] - mu) * rs * ga + be;
    xn[i] = v;
    m = fmaxf(m, v);
  }
  __shared__ float red[256];
  red[threadIdx.x] = m; __syncthreads();
  for (int off = 128; off > 0; off >>= 1) {
    if (threadIdx.x < off)
      red[threadIdx.x] = fmaxf(red[threadIdx.x], red[threadIdx.x + off]);
    __syncthreads();
  }
  m = red[0];
  __syncthreads();
  float s = 0.f;
  #pragma unroll
  for (int i = 0; i < 16; ++i) { xn[i] = __expf(xn[i] - m); s += xn[i]; }
  red[threadIdx.x] = s; __syncthreads();
  for (int off = 128; off > 0; off >>= 1) {
    if (threadIdx.x < off) red[threadIdx.x] += red[threadIdx.x + off];
    __syncthreads();
  }
  float inv = 1.f / red[0];
  #pragma unroll
  for (int i = 0; i < 16; ++i) o[threadIdx.x + i * 256] = xn[i] * inv;
}

// ---------------------------------------------------------------------------
// K4: content lambda. lam[b,k,v] = sum_n ksm[b,k,n] * v_norm[b,v,n].
// One block per (b, v); 16 accumulators (k) per thread, wave+LDS reduce.
// ---------------------------------------------------------------------------
__global__ __launch_bounds__(256) void k_lam(const float* __restrict__ proj,
    const float* __restrict__ ksm,
    const float* __restrict__ meanp, const float* __restrict__ rstdp,
    const float* __restrict__ gvg, const float* __restrict__ gvb,
    float* __restrict__ lam) {
  const int bv = blockIdx.x;  // b*64 + v
  const int b = bv >> 6, v = bv & 63;
  const int g = 20 + (v >> 2);
  const float mu = meanp[b * NG_ + g], rs = rstdp[b * NG_ + g];
  const float ga = gvg[v], be = gvb[v];
  const float* pv = proj + ((size_t)b * OTOT_ + 80 + v) * N_;
  const float* pk = ksm + (size_t)b * KK_ * N_;

  float acc[16];
  #pragma unroll
  for (int k = 0; k < 16; ++k) acc[k] = 0.f;
  for (int n = threadIdx.x; n < N_; n += 256) {
    float vn = (pv[n] - mu) * rs * ga + be;
    #pragma unroll
    for (int k = 0; k < 16; ++k) acc[k] += pk[(size_t)k * N_ + n] * vn;
  }
  __shared__ float red[64];
  const int lane = threadIdx.x & 63, wid = threadIdx.x >> 6;
  #pragma unroll
  for (int k = 0; k < 16; ++k) {
    float s = acc[k];
    #pragma unroll
    for (int off = 32; off > 0; off >>= 1) s += __shfl_down(s, off, 64);
    if (lane == 0) red[wid * 16 + k] = s;
  }
  __syncthreads();
  if (threadIdx.x < 16) {
    float s = red[threadIdx.x] + red[16 + threadIdx.x] +
              red[32 + threadIdx.x] + red[48 + threadIdx.x];
    lam[((size_t)b * KK_ + threadIdx.x) * VV_ + v] = s;
  }
}

// ---------------------------------------------------------------------------
// K5: fused position-conv + combine.
// out[b, h*64+v, n] = sum_k q_norm[b,h,k,n] * (lam[b,k,v] + ctx[b,k,v,n])
// ctx = 7x7 cross-correlation of v_norm with emb[k]. Block: one (b, 16x16
// spatial tile, 16 v's). q (64 ch) in registers; v tile (22x22+halo) in LDS.
// ---------------------------------------------------------------------------
__global__ __launch_bounds__(256) void k_final(const float* __restrict__ proj,
    const float* __restrict__ meanp, const float* __restrict__ rstdp,
    const float* __restrict__ gqg, const float* __restrict__ gqb,
    const float* __restrict__ gvg, const float* __restrict__ gvb,
    const float* __restrict__ emb, const float* __restrict__ lam,
    float* __restrict__ out) {
  const int tile = blockIdx.x;   // 0..15 -> 4x4 grid of 16x16 tiles
  const int vs   = blockIdx.y;   // 0..VSPLIT_-1
  const int b    = blockIdx.z;
  const int ty0 = (tile >> 2) * 16, tx0 = (tile & 3) * 16;
  const int tid = threadIdx.x;
  const int ty = tid >> 4, tx = tid & 15;
  const int n = (ty0 + ty) * W_ + (tx0 + tx);

  __shared__ float s_emb[16 * 49];
  __shared__ float s_lam[16 * 64];
  __shared__ float s_v[22][24];    // pad cols to 24 -> uniform 2-way (free)
  __shared__ float s_mu[NG_], s_rs[NG_];

  for (int i = tid; i < 784; i += 256)  s_emb[i] = emb[i];
  for (int i = tid; i < 1024; i += 256) s_lam[i] = lam[(size_t)b * 1024 + i];
  if (tid < NG_) { s_mu[tid] = meanp[b * NG_ + tid]; s_rs[tid] = rstdp[b * NG_ + tid]; }
  __syncthreads();

  const float* pb = proj + (size_t)b * OTOT_ * N_;
  float q[64];
  #pragma unroll
  for (int o = 0; o < 64; ++o) {
    int g = o >> 2;
    q[o] = (pb[(size_t)o * N_ + n] - s_mu[g]) * s_rs[g] * gqg[o] + gqb[o];
  }

  for (int vv = vs * (64 / VSPLIT_); vv < (vs + 1) * (64 / VSPLIT_); ++vv) {
    __syncthreads();
    const int g = 20 + (vv >> 2);
    const float mu = s_mu[g], rs = s_rs[g];
    const float ga = gvg[vv], be = gvb[vv];
    const float* pv = pb + (size_t)(80 + vv) * N_;
    for (int i = tid; i < 22 * 22; i += 256) {
      int ry = i / 22, rx = i % 22;
      int gy = ty0 - PAD_ + ry, gx = tx0 - PAD_ + rx;
      float val = 0.f;
      if (gy >= 0 && gy < H_ && gx >= 0 && gx < W_)
        val = (pv[gy * W_ + gx] - mu) * rs * ga + be;
      s_v[ry][rx] = val;
    }
    __syncthreads();

    float ctx[16];
    #pragma unroll
    for (int k = 0; k < 16; ++k) ctx[k] = s_lam[k * 64 + vv];
    #pragma unroll
    for (int i = 0; i < 7; ++i) {
      #pragma unroll
      for (int j = 0; j < 7; ++j) {
        float vval = s_v[ty + i][tx + j];
        const float* e = &s_emb[i * 7 + j];
        #pragma unroll
        for (int k = 0; k < 16; ++k) ctx[k] += e[k * 49] * vval;
      }
    }
    #pragma unroll
    for (int h = 0; h < 4; ++h) {
      float o_ = 0.f;
      #pragma unroll
      for (int k = 0; k < 16; ++k) o_ += q[h * 16 + k] * ctx[k];
      out[((size_t)b * 256 + h * 64 + vv) * (size_t)N_ + n] = o_;
    }
  }
}

// ---------------------------------------------------------------------------
extern "C" void kernel_launch(void* const* d_in, const int* in_sizes, int n_in,
                              void* d_out, int out_size, void* d_ws, size_t ws_size,
                              hipStream_t stream) {
  const float* x   = (const float*)d_in[0];
  const float* wq  = (const float*)d_in[1];
  const float* gqg = (const float*)d_in[2];
  const float* gqb = (const float*)d_in[3];
  const float* wk  = (const float*)d_in[4];
  const float* gkg = (const float*)d_in[5];
  const float* gkb = (const float*)d_in[6];
  const float* wv  = (const float*)d_in[7];
  const float* gvg = (const float*)d_in[8];
  const float* gvb = (const float*)d_in[9];
  const float* emb = (const float*)d_in[10];
  float* out = (float*)d_out;
  float* ws  = (float*)d_ws;

  float* proj  = ws;                                    // B*144*N floats
  float* meanp = proj + (size_t)B_ * OTOT_ * N_;        // B*36
  float* rstdp = meanp + B_ * NG_;                      // B*36
  float* ksm   = rstdp + B_ * NG_;                      // B*16*N
  float* lam   = ksm + (size_t)B_ * KK_ * N_;           // B*16*64

  k_proj<<<dim3(4, 9, B_), 256, 0, stream>>>(x, wq, wk, wv, proj);
  k_stats<<<dim3(B_ * NG_), 256, 0, stream>>>(proj, meanp, rstdp);
  k_softmax<<<dim3(B_ * KK_), 256, 0, stream>>>(proj, meanp, rstdp, gkg, gkb, ksm);
  k_lam<<<dim3(B_ * VV_), 256, 0, stream>>>(proj, ksm, meanp, rstdp, gvg, gvb, lam);
  k_final<<<dim3(16, VSPLIT_, B_), 256, 0, stream>>>(proj, meanp, rstdp,
      gqg, gqb, gvg, gvb, emb, lam, out);
}

// Round 4
// 339.818 us; speedup vs baseline: 1.1223x; 1.1223x over previous
//
#include <hip/hip_runtime.h>
#include <math.h>

#define B_    16
#define C_    256
#define H_    64
#define W_    64
#define N_    4096
#define HEADS_ 4
#define KK_   16
#define VV_   64
#define M_    7
#define PAD_  3
#define OTOT_ 144   // 64 q + 16 k + 64 v channels
#define NG_   36    // 36 groups of 4 channels
#define EPS_  1e-5f

// ---------------------------------------------------------------------------
// K1: fused projection GEMM. proj[b, o, n] = sum_c W[o,c] * x[b,c,n]
// o in [0,144): 0-63 = q (wq), 64-79 = k (wk), 80-143 = v (wv)
// ---------------------------------------------------------------------------
__global__ __launch_bounds__(256) void k_proj(const float* __restrict__ x,
    const float* __restrict__ wq, const float* __restrict__ wk,
    const float* __restrict__ wv, float* __restrict__ proj) {
  __shared__ float sw[16][256];
  const int tid = threadIdx.x;
  const int o0  = blockIdx.y * 16;
  const int b   = blockIdx.z;
  const int n0  = blockIdx.x * 1024 + tid;

  for (int r = 0; r < 16; ++r) {
    int o = o0 + r;
    const float* wrow = (o < 64) ? (wq + o * C_)
                       : ((o < 80) ? (wk + (o - 64) * C_) : (wv + (o - 80) * C_));
    sw[r][tid] = wrow[tid];  // blockDim == C_ == 256
  }
  __syncthreads();

  float acc[16][4];
  #pragma unroll
  for (int r = 0; r < 16; ++r)
    #pragma unroll
    for (int p = 0; p < 4; ++p) acc[r][p] = 0.f;

  const float* xb = x + (size_t)b * C_ * N_;
  for (int c0 = 0; c0 < C_; c0 += 4) {
    float xv[4][4];
    #pragma unroll
    for (int i = 0; i < 4; ++i)
      #pragma unroll
      for (int p = 0; p < 4; ++p)
        xv[i][p] = xb[(size_t)(c0 + i) * N_ + n0 + p * 256];
    #pragma unroll
    for (int i = 0; i < 4; ++i) {
      #pragma unroll
      for (int r = 0; r < 16; ++r) {
        float w = sw[r][c0 + i];
        #pragma unroll
        for (int p = 0; p < 4; ++p) acc[r][p] += w * xv[i][p];
      }
    }
  }

  float* pb = proj + ((size_t)b * OTOT_ + o0) * N_ + n0;
  #pragma unroll
  for (int r = 0; r < 16; ++r)
    #pragma unroll
    for (int p = 0; p < 4; ++p)
      pb[(size_t)r * N_ + p * 256] = acc[r][p];
}

// ---------------------------------------------------------------------------
// K2: GroupNorm stats. One block per (b, group).
// ---------------------------------------------------------------------------
__global__ __launch_bounds__(256) void k_stats(const float* __restrict__ proj,
    float* __restrict__ meanp, float* __restrict__ rstdp) {
  const int bg = blockIdx.x;           // b*36 + g
  const int b = bg / NG_, g = bg % NG_;
  const float* p = proj + ((size_t)b * OTOT_ + g * 4) * N_;
  float s = 0.f, s2 = 0.f;
  for (int i = threadIdx.x; i < 4 * N_; i += 256) {
    float v = p[i];
    s += v; s2 += v * v;
  }
  __shared__ float rs[256], rq[256];
  rs[threadIdx.x] = s; rq[threadIdx.x] = s2;
  __syncthreads();
  for (int off = 128; off > 0; off >>= 1) {
    if (threadIdx.x < off) {
      rs[threadIdx.x] += rs[threadIdx.x + off];
      rq[threadIdx.x] += rq[threadIdx.x + off];
    }
    __syncthreads();
  }
  if (threadIdx.x == 0) {
    float m   = rs[0] * (1.f / 16384.f);
    float var = rq[0] * (1.f / 16384.f) - m * m;
    meanp[bg] = m;
    rstdp[bg] = rsqrtf(var + EPS_);
  }
}

// ---------------------------------------------------------------------------
// K3: k GroupNorm-apply + softmax over n. One block per (b, kk) row.
// ---------------------------------------------------------------------------
__global__ __launch_bounds__(256) void k_softmax(const float* __restrict__ proj,
    const float* __restrict__ meanp, const float* __restrict__ rstdp,
    const float* __restrict__ gkg, const float* __restrict__ gkb,
    float* __restrict__ ksm) {
  const int bk = blockIdx.x;  // b*16 + kk
  const int b = bk >> 4, kk = bk & 15;
  const int g = 16 + (kk >> 2);
  const float mu = meanp[b * NG_ + g], rs = rstdp[b * NG_ + g];
  const float ga = gkg[kk], be = gkb[kk];
  const float* p = proj + ((size_t)b * OTOT_ + 64 + kk) * N_;
  float* o = ksm + ((size_t)b * KK_ + kk) * N_;

  float xn[16];
  float m = -1e30f;
  #pragma unroll
  for (int i = 0; i < 16; ++i) {
    float v = (p[threadIdx.x + i * 256] - mu) * rs * ga + be;
    xn[i] = v;
    m = fmaxf(m, v);
  }
  __shared__ float red[256];
  red[threadIdx.x] = m; __syncthreads();
  for (int off = 128; off > 0; off >>= 1) {
    if (threadIdx.x < off)
      red[threadIdx.x] = fmaxf(red[threadIdx.x], red[threadIdx.x + off]);
    __syncthreads();
  }
  m = red[0];
  __syncthreads();
  float s = 0.f;
  #pragma unroll
  for (int i = 0; i < 16; ++i) { xn[i] = __expf(xn[i] - m); s += xn[i]; }
  red[threadIdx.x] = s; __syncthreads();
  for (int off = 128; off > 0; off >>= 1) {
    if (threadIdx.x < off) red[threadIdx.x] += red[threadIdx.x + off];
    __syncthreads();
  }
  float inv = 1.f / red[0];
  #pragma unroll
  for (int i = 0; i < 16; ++i) o[threadIdx.x + i * 256] = xn[i] * inv;
}

// ---------------------------------------------------------------------------
// K4: content lambda. lam[b,k,v] = sum_n ksm[b,k,n] * v_norm[b,v,n].
// ---------------------------------------------------------------------------
__global__ __launch_bounds__(256) void k_lam(const float* __restrict__ proj,
    const float* __restrict__ ksm,
    const float* __restrict__ meanp, const float* __restrict__ rstdp,
    const float* __restrict__ gvg, const float* __restrict__ gvb,
    float* __restrict__ lam) {
  const int bv = blockIdx.x;  // b*64 + v
  const int b = bv >> 6, v = bv & 63;
  const int g = 20 + (v >> 2);
  const float mu = meanp[b * NG_ + g], rs = rstdp[b * NG_ + g];
  const float ga = gvg[v], be = gvb[v];
  const float* pv = proj + ((size_t)b * OTOT_ + 80 + v) * N_;
  const float* pk = ksm + (size_t)b * KK_ * N_;

  float acc[16];
  #pragma unroll
  for (int k = 0; k < 16; ++k) acc[k] = 0.f;
  for (int n = threadIdx.x; n < N_; n += 256) {
    float vn = (pv[n] - mu) * rs * ga + be;
    #pragma unroll
    for (int k = 0; k < 16; ++k) acc[k] += pk[(size_t)k * N_ + n] * vn;
  }
  __shared__ float red[64];
  const int lane = threadIdx.x & 63, wid = threadIdx.x >> 6;
  #pragma unroll
  for (int k = 0; k < 16; ++k) {
    float s = acc[k];
    #pragma unroll
    for (int off = 32; off > 0; off >>= 1) s += __shfl_down(s, off, 64);
    if (lane == 0) red[wid * 16 + k] = s;
  }
  __syncthreads();
  if (threadIdx.x < 16) {
    float s = red[threadIdx.x] + red[16 + threadIdx.x] +
              red[32 + threadIdx.x] + red[48 + threadIdx.x];
    lam[((size_t)b * KK_ + threadIdx.x) * VV_ + v] = s;
  }
}

// ---------------------------------------------------------------------------
// K5: fused position-conv + combine, k-contraction FIRST.
// Per thread (one position n, one head h):
//   qn[k]  = GN(q)[h,k,n]                       (16 regs)
//   qe[t]  = sum_k qn[k] * emb[k,t]             (49 regs, computed once)
//   out[h,v,n] = sum_k qn[k]*lam[k,v]  +  sum_t qe[t]*v_norm[n+off(t)]
// Block: (row-strip of 4 rows x 64 cols, head h, batch b). v staged in
// batches of 4 into LDS. All global I/O coalesced (lane = x coordinate).
// ---------------------------------------------------------------------------
#define VB_ 4
__global__ __launch_bounds__(256) void k_final(const float* __restrict__ proj,
    const float* __restrict__ meanp, const float* __restrict__ rstdp,
    const float* __restrict__ gqg, const float* __restrict__ gqb,
    const float* __restrict__ gvg, const float* __restrict__ gvb,
    const float* __restrict__ emb, const float* __restrict__ lam,
    float* __restrict__ out) {
  const int strip = blockIdx.x;       // 16 strips of 4 rows
  const int h     = blockIdx.y;       // head
  const int b     = blockIdx.z;
  const int r0    = strip * 4;
  const int tid = threadIdx.x;
  const int ty = tid >> 6, tx = tid & 63;   // lane = x -> coalesced
  const int n = (r0 + ty) * W_ + tx;

  __shared__ float s_emb[16 * 49];
  __shared__ float s_lam[16 * 64];
  __shared__ float s_mu[NG_], s_rs[NG_];
  __shared__ float s_v[VB_][10][72];        // 4 v-channels, 10x70 halo tile

  for (int i = tid; i < 784; i += 256)  s_emb[i] = emb[i];
  for (int i = tid; i < 1024; i += 256) s_lam[i] = lam[(size_t)b * 1024 + i];
  if (tid < NG_) { s_mu[tid] = meanp[b * NG_ + tid]; s_rs[tid] = rstdp[b * NG_ + tid]; }
  __syncthreads();

  const float* pb = proj + (size_t)b * OTOT_ * N_;

  // qn: GroupNormed q for this head, 16 k's
  float qn[16];
  #pragma unroll
  for (int k = 0; k < 16; ++k) {
    int o = h * 16 + k;
    int g = o >> 2;
    qn[k] = (pb[(size_t)o * N_ + n] - s_mu[g]) * s_rs[g] * gqg[o] + gqb[o];
  }
  // qe: contract k into the 49 taps (once per thread)
  float qe[49];
  #pragma unroll
  for (int t = 0; t < 49; ++t) {
    float s = 0.f;
    #pragma unroll
    for (int k = 0; k < 16; ++k) s += qn[k] * s_emb[k * 49 + t];
    qe[t] = s;
  }

  for (int v0 = 0; v0 < VV_; v0 += VB_) {
    __syncthreads();
    // stage VB_ v-channel halo tiles (10 rows x 70 cols each), GN applied
    for (int i = tid; i < VB_ * 700; i += 256) {
      int vb = i / 700;
      int rem = i - vb * 700;
      int ry = rem / 70;
      int rx = rem - ry * 70;
      int v = v0 + vb;
      int g = 20 + (v >> 2);
      int gy = r0 - PAD_ + ry;
      int gx = rx - PAD_;
      float val = 0.f;
      if (gy >= 0 && gy < H_ && gx >= 0 && gx < W_)
        val = (pb[(size_t)(80 + v) * N_ + gy * W_ + gx] - s_mu[g]) * s_rs[g]
              * gvg[v] + gvb[v];
      s_v[vb][ry][rx] = val;
    }
    __syncthreads();

    #pragma unroll
    for (int vb = 0; vb < VB_; ++vb) {
      const int v = v0 + vb;
      // content: sum_k qn[k] * lam[k,v]   (lam broadcast reads)
      float acc = 0.f;
      #pragma unroll
      for (int k = 0; k < 16; ++k) acc += qn[k] * s_lam[k * 64 + v];
      // context: sum_t qe[t] * v_tile
      #pragma unroll
      for (int i = 0; i < 7; ++i) {
        #pragma unroll
        for (int j = 0; j < 7; ++j)
          acc += qe[i * 7 + j] * s_v[vb][ty + i][tx + j];
      }
      out[((size_t)b * 256 + h * 64 + v) * (size_t)N_ + n] = acc;
    }
  }
}

// ---------------------------------------------------------------------------
extern "C" void kernel_launch(void* const* d_in, const int* in_sizes, int n_in,
                              void* d_out, int out_size, void* d_ws, size_t ws_size,
                              hipStream_t stream) {
  const float* x   = (const float*)d_in[0];
  const float* wq  = (const float*)d_in[1];
  const float* gqg = (const float*)d_in[2];
  const float* gqb = (const float*)d_in[3];
  const float* wk  = (const float*)d_in[4];
  const float* gkg = (const float*)d_in[5];
  const float* gkb = (const float*)d_in[6];
  const float* wv  = (const float*)d_in[7];
  const float* gvg = (const float*)d_in[8];
  const float* gvb = (const float*)d_in[9];
  const float* emb = (const float*)d_in[10];
  float* out = (float*)d_out;
  float* ws  = (float*)d_ws;

  float* proj  = ws;                                    // B*144*N floats
  float* meanp = proj + (size_t)B_ * OTOT_ * N_;        // B*36
  float* rstdp = meanp + B_ * NG_;                      // B*36
  float* ksm   = rstdp + B_ * NG_;                      // B*16*N
  float* lam   = ksm + (size_t)B_ * KK_ * N_;           // B*16*64

  k_proj<<<dim3(4, 9, B_), 256, 0, stream>>>(x, wq, wk, wv, proj);
  k_stats<<<dim3(B_ * NG_), 256, 0, stream>>>(proj, meanp, rstdp);
  k_softmax<<<dim3(B_ * KK_), 256, 0, stream>>>(proj, meanp, rstdp, gkg, gkb, ksm);
  k_lam<<<dim3(B_ * VV_), 256, 0, stream>>>(proj, ksm, meanp, rstdp, gvg, gvb, lam);
  k_final<<<dim3(16, HEADS_, B_), 256, 0, stream>>>(proj, meanp, rstdp,
      gqg, gqb, gvg, gvb, emb, lam, out);
}

// Round 5
// 301.129 us; speedup vs baseline: 1.2665x; 1.1285x over previous
//
#include <hip/hip_runtime.h>
#include <math.h>

#define B_    16
#define C_    256
#define H_    64
#define W_    64
#define N_    4096
#define HEADS_ 4
#define KK_   16
#define VV_   64
#define M_    7
#define PAD_  3
#define OTOT_ 144   // 64 q + 16 k + 64 v channels
#define NG_   36    // 36 groups of 4 channels
#define EPS_  1e-5f

// bf16 helpers (round-half-up; error ~2^-9 relative, fine vs threshold)
__device__ inline unsigned packbf(float a, float b) {
  unsigned ua = __float_as_uint(a) + 0x8000u;
  unsigned ub = __float_as_uint(b) + 0x8000u;
  return (ua >> 16) | (ub & 0xffff0000u);
}
__device__ inline float bflo(unsigned u) { return __uint_as_float(u << 16); }
__device__ inline float bfhi(unsigned u) { return __uint_as_float(u & 0xffff0000u); }

// ---------------------------------------------------------------------------
// K1: fused projection GEMM. proj[b, o, n] = sum_c W[o,c] * x[b,c,n]
// ---------------------------------------------------------------------------
__global__ __launch_bounds__(256) void k_proj(const float* __restrict__ x,
    const float* __restrict__ wq, const float* __restrict__ wk,
    const float* __restrict__ wv, float* __restrict__ proj) {
  __shared__ float sw[16][256];
  const int tid = threadIdx.x;
  const int o0  = blockIdx.y * 16;
  const int b   = blockIdx.z;
  const int n0  = blockIdx.x * 1024 + tid;

  for (int r = 0; r < 16; ++r) {
    int o = o0 + r;
    const float* wrow = (o < 64) ? (wq + o * C_)
                       : ((o < 80) ? (wk + (o - 64) * C_) : (wv + (o - 80) * C_));
    sw[r][tid] = wrow[tid];
  }
  __syncthreads();

  float acc[16][4];
  #pragma unroll
  for (int r = 0; r < 16; ++r)
    #pragma unroll
    for (int p = 0; p < 4; ++p) acc[r][p] = 0.f;

  const float* xb = x + (size_t)b * C_ * N_;
  for (int c0 = 0; c0 < C_; c0 += 4) {
    float xv[4][4];
    #pragma unroll
    for (int i = 0; i < 4; ++i)
      #pragma unroll
      for (int p = 0; p < 4; ++p)
        xv[i][p] = xb[(size_t)(c0 + i) * N_ + n0 + p * 256];
    #pragma unroll
    for (int i = 0; i < 4; ++i) {
      #pragma unroll
      for (int r = 0; r < 16; ++r) {
        float w = sw[r][c0 + i];
        #pragma unroll
        for (int p = 0; p < 4; ++p) acc[r][p] += w * xv[i][p];
      }
    }
  }

  float* pb = proj + ((size_t)b * OTOT_ + o0) * N_ + n0;
  #pragma unroll
  for (int r = 0; r < 16; ++r)
    #pragma unroll
    for (int p = 0; p < 4; ++p)
      pb[(size_t)r * N_ + p * 256] = acc[r][p];
}

// ---------------------------------------------------------------------------
// K2: GroupNorm stats. One block per (b, group).
// ---------------------------------------------------------------------------
__global__ __launch_bounds__(256) void k_stats(const float* __restrict__ proj,
    float* __restrict__ meanp, float* __restrict__ rstdp) {
  const int bg = blockIdx.x;
  const int b = bg / NG_, g = bg % NG_;
  const float* p = proj + ((size_t)b * OTOT_ + g * 4) * N_;
  float s = 0.f, s2 = 0.f;
  for (int i = threadIdx.x; i < 4 * N_; i += 256) {
    float v = p[i];
    s += v; s2 += v * v;
  }
  __shared__ float rs[256], rq[256];
  rs[threadIdx.x] = s; rq[threadIdx.x] = s2;
  __syncthreads();
  for (int off = 128; off > 0; off >>= 1) {
    if (threadIdx.x < off) {
      rs[threadIdx.x] += rs[threadIdx.x + off];
      rq[threadIdx.x] += rq[threadIdx.x + off];
    }
    __syncthreads();
  }
  if (threadIdx.x == 0) {
    float m   = rs[0] * (1.f / 16384.f);
    float var = rq[0] * (1.f / 16384.f) - m * m;
    meanp[bg] = m;
    rstdp[bg] = rsqrtf(var + EPS_);
  }
}

// ---------------------------------------------------------------------------
// K3: k GroupNorm-apply + softmax over n.
// ---------------------------------------------------------------------------
__global__ __launch_bounds__(256) void k_softmax(const float* __restrict__ proj,
    const float* __restrict__ meanp, const float* __restrict__ rstdp,
    const float* __restrict__ gkg, const float* __restrict__ gkb,
    float* __restrict__ ksm) {
  const int bk = blockIdx.x;
  const int b = bk >> 4, kk = bk & 15;
  const int g = 16 + (kk >> 2);
  const float mu = meanp[b * NG_ + g], rs = rstdp[b * NG_ + g];
  const float ga = gkg[kk], be = gkb[kk];
  const float* p = proj + ((size_t)b * OTOT_ + 64 + kk) * N_;
  float* o = ksm + ((size_t)b * KK_ + kk) * N_;

  float xn[16];
  float m = -1e30f;
  #pragma unroll
  for (int i = 0; i < 16; ++i) {
    float v = (p[threadIdx.x + i * 256] - mu) * rs * ga + be;
    xn[i] = v;
    m = fmaxf(m, v);
  }
  __shared__ float red[256];
  red[threadIdx.x] = m; __syncthreads();
  for (int off = 128; off > 0; off >>= 1) {
    if (threadIdx.x < off)
      red[threadIdx.x] = fmaxf(red[threadIdx.x], red[threadIdx.x + off]);
    __syncthreads();
  }
  m = red[0];
  __syncthreads();
  float s = 0.f;
  #pragma unroll
  for (int i = 0; i < 16; ++i) { xn[i] = __expf(xn[i] - m); s += xn[i]; }
  red[threadIdx.x] = s; __syncthreads();
  for (int off = 128; off > 0; off >>= 1) {
    if (threadIdx.x < off) red[threadIdx.x] += red[threadIdx.x + off];
    __syncthreads();
  }
  float inv = 1.f / red[0];
  #pragma unroll
  for (int i = 0; i < 16; ++i) o[threadIdx.x + i * 256] = xn[i] * inv;
}

// ---------------------------------------------------------------------------
// K4: content lambda. lam[b,k,v] = sum_n ksm[b,k,n] * v_norm[b,v,n].
// ---------------------------------------------------------------------------
__global__ __launch_bounds__(256) void k_lam(const float* __restrict__ proj,
    const float* __restrict__ ksm,
    const float* __restrict__ meanp, const float* __restrict__ rstdp,
    const float* __restrict__ gvg, const float* __restrict__ gvb,
    float* __restrict__ lam) {
  const int bv = blockIdx.x;
  const int b = bv >> 6, v = bv & 63;
  const int g = 20 + (v >> 2);
  const float mu = meanp[b * NG_ + g], rs = rstdp[b * NG_ + g];
  const float ga = gvg[v], be = gvb[v];
  const float* pv = proj + ((size_t)b * OTOT_ + 80 + v) * N_;
  const float* pk = ksm + (size_t)b * KK_ * N_;

  float acc[16];
  #pragma unroll
  for (int k = 0; k < 16; ++k) acc[k] = 0.f;
  for (int n = threadIdx.x; n < N_; n += 256) {
    float vn = (pv[n] - mu) * rs * ga + be;
    #pragma unroll
    for (int k = 0; k < 16; ++k) acc[k] += pk[(size_t)k * N_ + n] * vn;
  }
  __shared__ float red[64];
  const int lane = threadIdx.x & 63, wid = threadIdx.x >> 6;
  #pragma unroll
  for (int k = 0; k < 16; ++k) {
    float s = acc[k];
    #pragma unroll
    for (int off = 32; off > 0; off >>= 1) s += __shfl_down(s, off, 64);
    if (lane == 0) red[wid * 16 + k] = s;
  }
  __syncthreads();
  if (threadIdx.x < 16) {
    float s = red[threadIdx.x] + red[16 + threadIdx.x] +
              red[32 + threadIdx.x] + red[48 + threadIdx.x];
    lam[((size_t)b * KK_ + threadIdx.x) * VV_ + v] = s;
  }
}

// ---------------------------------------------------------------------------
// K5 v3: fused position-conv + combine, wide-LDS edition.
// Tile: 4 rows x 64 cols, one head, one batch. 256 threads =
//   vlane(4) x ty(4) x txg(16); thread owns 4 pixels (x = 4*txg..+3) and
//   16 v-channels (vlane + 4j).
// qe[49] per position computed once -> LDS bf16 [49][256] (b64 reads).
// v-halo staged bf16 [16ch][10][72] per phase (b64 reads, 12-float windows).
// Per (v,row): 3 b64 v-reads + amortized 7/4 b64 qe-reads + 28 FMA.
// ---------------------------------------------------------------------------
__global__ __launch_bounds__(256) void k_final(const float* __restrict__ proj,
    const float* __restrict__ meanp, const float* __restrict__ rstdp,
    const float* __restrict__ gqg, const float* __restrict__ gqb,
    const float* __restrict__ gvg, const float* __restrict__ gvb,
    const float* __restrict__ emb, const float* __restrict__ lam,
    float* __restrict__ out) {
  const int strip = blockIdx.x;       // 16 strips of 4 rows
  const int h     = blockIdx.y;
  const int b     = blockIdx.z;
  const int r0    = strip * 4;
  const int tid   = threadIdx.x;
  const int vlane = tid >> 6;         // 0..3 (= wave id)
  const int slot  = tid & 63;
  const int ty    = slot >> 4;        // 0..3
  const int txg   = slot & 15;        // 0..15
  const int x0    = txg << 2;
  const int y     = r0 + ty;
  const int n0    = y * W_ + x0;
  const int pos4  = ty * 64 + x0;     // position index of pixel 0 (mult of 4)

  __shared__ unsigned short s_qe[49 * 256];   // bf16 qe[t][pos]
  __shared__ unsigned short s_v[16 * 720];    // bf16 v[ch][10][72]
  __shared__ float s_lam[16 * 64];
  __shared__ float s_mu[NG_], s_rs[NG_];
  __shared__ float s_gvw[64], s_gvb[64];

  float* s_emb = reinterpret_cast<float*>(s_v);  // alias: phase-0 only

  for (int i = tid; i < 784; i += 256)  s_emb[i] = emb[i];
  for (int i = tid; i < 1024; i += 256) s_lam[i] = lam[(size_t)b * 1024 + i];
  if (tid < NG_) { s_mu[tid] = meanp[b * NG_ + tid]; s_rs[tid] = rstdp[b * NG_ + tid]; }
  if (tid < 64)  { s_gvw[tid] = gvg[tid]; s_gvb[tid] = gvb[tid]; }
  __syncthreads();

  const float* pb = proj + (size_t)b * OTOT_ * N_;

  // ---- qn: GroupNormed q, 4 pixels x 16 k (float4 loads, 16B aligned)
  float qn[4][16];
  #pragma unroll
  for (int k = 0; k < 16; ++k) {
    const int o = h * 16 + k, g = o >> 2;
    const float mu = s_mu[g], rs = s_rs[g];
    const float ga = gqg[o], be = gqb[o];
    const float4 qv = *reinterpret_cast<const float4*>(pb + (size_t)o * N_ + n0);
    qn[0][k] = (qv.x - mu) * rs * ga + be;
    qn[1][k] = (qv.y - mu) * rs * ga + be;
    qn[2][k] = (qv.z - mu) * rs * ga + be;
    qn[3][k] = (qv.w - mu) * rs * ga + be;
  }

  // ---- qe: taps split across vlanes; bf16-pack 4 pixels -> LDS
  {
    const int t0 = vlane * 13;
    const int t1 = (t0 + 13 < 49) ? (t0 + 13) : 49;
    for (int t = t0; t < t1; ++t) {
      float p0 = 0.f, p1 = 0.f, p2 = 0.f, p3 = 0.f;
      #pragma unroll
      for (int k = 0; k < 16; ++k) {
        const float e = s_emb[k * 49 + t];
        p0 += qn[0][k] * e; p1 += qn[1][k] * e;
        p2 += qn[2][k] * e; p3 += qn[3][k] * e;
      }
      uint2 pk;
      pk.x = packbf(p0, p1);
      pk.y = packbf(p2, p3);
      *reinterpret_cast<uint2*>(&s_qe[t * 256 + pos4]) = pk;
    }
  }

  // ---- 4 phases x 16 v-channels
  for (int ph = 0; ph < 4; ++ph) {
    __syncthreads();   // protect s_v (incl. emb alias) + s_qe readiness
    // stage: 16 channels, rows r0-3..r0+6, x -4..67 (72 = 18 float4, each
    // fully in- or out-of-image). GN applied in-flight, bf16 ds_write_b64.
    for (int i = tid; i < 16 * 180; i += 256) {
      const int vh  = i / 180;
      const int rem = i - vh * 180;
      const int ry  = rem / 18;
      const int rx4 = rem - ry * 18;
      const int v   = ph * 16 + vh;
      const int g   = 20 + (v >> 2);
      const int gy  = r0 - 3 + ry;
      float4 f = make_float4(0.f, 0.f, 0.f, 0.f);
      if (gy >= 0 && gy < H_ && rx4 >= 1 && rx4 <= 16) {
        const int gx0 = (rx4 << 2) - 4;
        f = *reinterpret_cast<const float4*>(pb + (size_t)(80 + v) * N_ + gy * W_ + gx0);
        const float mu = s_mu[g], rs = s_rs[g], ga = s_gvw[v], be = s_gvb[v];
        f.x = (f.x - mu) * rs * ga + be;
        f.y = (f.y - mu) * rs * ga + be;
        f.z = (f.z - mu) * rs * ga + be;
        f.w = (f.w - mu) * rs * ga + be;
      }
      uint2 w;
      w.x = packbf(f.x, f.y);
      w.y = packbf(f.z, f.w);
      *reinterpret_cast<uint2*>(&s_v[vh * 720 + ry * 72 + (rx4 << 2)]) = w;
    }
    __syncthreads();

    // accumulators init = content term (lam broadcast, qn in regs)
    float acc[4][4];
    #pragma unroll
    for (int vj = 0; vj < 4; ++vj) {
      const int v = ph * 16 + vj * 4 + vlane;
      float a0 = 0.f, a1 = 0.f, a2 = 0.f, a3 = 0.f;
      #pragma unroll
      for (int k = 0; k < 16; ++k) {
        const float lv = s_lam[k * 64 + v];
        a0 += qn[0][k] * lv; a1 += qn[1][k] * lv;
        a2 += qn[2][k] * lv; a3 += qn[3][k] * lv;
      }
      acc[vj][0] = a0; acc[vj][1] = a1; acc[vj][2] = a2; acc[vj][3] = a3;
    }

    // conv: 7 rows; qe row unpacked once, reused across 4 v's
    #pragma unroll
    for (int i = 0; i < 7; ++i) {
      float qeu[7][4];
      #pragma unroll
      for (int j = 0; j < 7; ++j) {
        const uint2 pk = *reinterpret_cast<const uint2*>(&s_qe[(i * 7 + j) * 256 + pos4]);
        qeu[j][0] = bflo(pk.x); qeu[j][1] = bfhi(pk.x);
        qeu[j][2] = bflo(pk.y); qeu[j][3] = bfhi(pk.y);
      }
      #pragma unroll
      for (int vj = 0; vj < 4; ++vj) {
        const int vh = vj * 4 + vlane;
        const unsigned short* sv = &s_v[vh * 720 + (ty + i) * 72 + x0];
        const uint2 wa = *reinterpret_cast<const uint2*>(sv);
        const uint2 wb = *reinterpret_cast<const uint2*>(sv + 4);
        const uint2 wc = *reinterpret_cast<const uint2*>(sv + 8);
        float wv[12];
        wv[0] = bflo(wa.x); wv[1] = bfhi(wa.x); wv[2]  = bflo(wa.y); wv[3]  = bfhi(wa.y);
        wv[4] = bflo(wb.x); wv[5] = bfhi(wb.x); wv[6]  = bflo(wb.y); wv[7]  = bfhi(wb.y);
        wv[8] = bflo(wc.x); wv[9] = bfhi(wc.x); wv[10] = bflo(wc.y); wv[11] = bfhi(wc.y);
        #pragma unroll
        for (int j = 0; j < 7; ++j)
          #pragma unroll
          for (int p = 0; p < 4; ++p)
            acc[vj][p] += qeu[j][p] * wv[p + j + 1];
      }
    }

    // store (float4, coalesced)
    #pragma unroll
    for (int vj = 0; vj < 4; ++vj) {
      const int v = ph * 16 + vj * 4 + vlane;
      float4 o4 = make_float4(acc[vj][0], acc[vj][1], acc[vj][2], acc[vj][3]);
      *reinterpret_cast<float4*>(out + ((size_t)b * 256 + h * 64 + v) * N_ + n0) = o4;
    }
  }
}

// ---------------------------------------------------------------------------
extern "C" void kernel_launch(void* const* d_in, const int* in_sizes, int n_in,
                              void* d_out, int out_size, void* d_ws, size_t ws_size,
                              hipStream_t stream) {
  const float* x   = (const float*)d_in[0];
  const float* wq  = (const float*)d_in[1];
  const float* gqg = (const float*)d_in[2];
  const float* gqb = (const float*)d_in[3];
  const float* wk  = (const float*)d_in[4];
  const float* gkg = (const float*)d_in[5];
  const float* gkb = (const float*)d_in[6];
  const float* wv  = (const float*)d_in[7];
  const float* gvg = (const float*)d_in[8];
  const float* gvb = (const float*)d_in[9];
  const float* emb = (const float*)d_in[10];
  float* out = (float*)d_out;
  float* ws  = (float*)d_ws;

  float* proj  = ws;                                    // B*144*N floats
  float* meanp = proj + (size_t)B_ * OTOT_ * N_;        // B*36
  float* rstdp = meanp + B_ * NG_;                      // B*36
  float* ksm   = rstdp + B_ * NG_;                      // B*16*N
  float* lam   = ksm + (size_t)B_ * KK_ * N_;           // B*16*64

  k_proj<<<dim3(4, 9, B_), 256, 0, stream>>>(x, wq, wk, wv, proj);
  k_stats<<<dim3(B_ * NG_), 256, 0, stream>>>(proj, meanp, rstdp);
  k_softmax<<<dim3(B_ * KK_), 256, 0, stream>>>(proj, meanp, rstdp, gkg, gkb, ksm);
  k_lam<<<dim3(B_ * VV_), 256, 0, stream>>>(proj, ksm, meanp, rstdp, gvg, gvb, lam);
  k_final<<<dim3(16, HEADS_, B_), 256, 0, stream>>>(proj, meanp, rstdp,
      gqg, gqb, gvg, gvb, emb, lam, out);
}